// Round 5
// baseline (444.619 us; speedup 1.0000x reference)
//
#include <hip/hip_runtime.h>

typedef unsigned short u16;
typedef unsigned int u32;
typedef __attribute__((ext_vector_type(8))) short short8v;
typedef __attribute__((ext_vector_type(4))) float float4v;

__device__ __forceinline__ float sigm(float x) { return 1.0f / (1.0f + __expf(-x)); }
__device__ __forceinline__ u16 f2bf(float f) {
  u32 u = __float_as_uint(f);
  u32 r = (u + 0x7fffu + ((u >> 16) & 1u)) >> 16;
  return (u16)r;
}
__device__ __forceinline__ float bf2f(u16 w) { return __uint_as_float(((u32)w) << 16); }

__global__ void k_cnt(const int* __restrict__ dst, int* __restrict__ cnt, int E) {
  int e = blockIdx.x * blockDim.x + threadIdx.x;
  if (e < E) atomicAdd(&cnt[dst[e]], 1);
}

// --- parallel scan: scan1 block sums -> scan2 scan of ~98 sums -> scan3 local scan ---
__global__ void k_scan1(const int* __restrict__ cnt, int* __restrict__ bsum, int N) {
  __shared__ int ws[4];
  int t = threadIdx.x;
  int i = blockIdx.x * 256 + t;
  int v = (i < N) ? cnt[i] : 0;
  int s = v;
  for (int off = 1; off < 64; off <<= 1) s += __shfl_xor(s, off);
  int wid = t >> 6, lane = t & 63;
  if (lane == 0) ws[wid] = s;
  __syncthreads();
  if (t == 0) bsum[blockIdx.x] = ws[0] + ws[1] + ws[2] + ws[3];
}

__global__ void k_scan2(int* __restrict__ bsum, int* __restrict__ row, int nb, int N) {
  __shared__ int s[256];
  int t = threadIdx.x;
  if (t < nb) s[t] = bsum[t];
  __syncthreads();
  if (t == 0) {
    int run = 0;
    for (int i = 0; i < nb; ++i) { int x = s[i]; s[i] = run; run += x; }
    row[N] = run;
  }
  __syncthreads();
  if (t < nb) bsum[t] = s[t];
}

__global__ void k_scan3(const int* __restrict__ cnt, const int* __restrict__ bsum,
                        int* __restrict__ row, int* __restrict__ cursor, int N) {
  __shared__ int ws[4];
  int t = threadIdx.x;
  int i = blockIdx.x * 256 + t;
  int v = (i < N) ? cnt[i] : 0;
  int lane = t & 63, wid = t >> 6;
  int incl = v;
  for (int off = 1; off < 64; off <<= 1) {
    int u = __shfl_up(incl, off);
    if (lane >= off) incl += u;
  }
  if (lane == 63) ws[wid] = incl;
  __syncthreads();
  int woff = bsum[blockIdx.x];
  for (int w = 0; w < wid; ++w) woff += ws[w];
  int excl = woff + incl - v;
  if (i < N) { row[i] = excl; cursor[i] = excl; }
}

// pos[e] = CSR slot of edge e (counting sort position among same-dst edges)
__global__ void k_pos(const int* __restrict__ dst, int* __restrict__ cursor,
                      int* __restrict__ pos, int E) {
  int e = blockIdx.x * blockDim.x + threadIdx.x;
  if (e < E) pos[e] = atomicAdd(&cursor[dst[e]], 1);
}

// hmid -> plain bf16; 2 edges/block, ea computed once in LDS   [verified r18]
__global__ __launch_bounds__(256) void k_edge_mlp(
    const float* __restrict__ ea_in, const float* __restrict__ Wea,
    const float* __restrict__ bea, const float* __restrict__ We1,
    const float* __restrict__ be1, u16* __restrict__ Ahi, int E) {
  __shared__ float att[2][19];
  __shared__ float ea[2][12];
  int half = threadIdx.x >> 7;
  int t = threadIdx.x & 127;
  int e = blockIdx.x * 2 + half;
  bool real = (e < E);
  int ee = real ? e : E - 1;
  if (t < 19) att[half][t] = ea_in[(size_t)ee * 19 + t];
  __syncthreads();
  if (t < 12) {
    float a = bea[t];
#pragma unroll
    for (int k = 0; k < 19; ++k) a += att[half][k] * Wea[k * 12 + t];
    ea[half][t] = fmaxf(a, 0.0f);
  }
  __syncthreads();
  float a = be1[t];
#pragma unroll
  for (int j = 0; j < 12; ++j) a += ea[half][j] * We1[j * 128 + t];
  if (real) Ahi[(size_t)e * 128 + t] = f2bf(fmaxf(a, 0.0f));
}

// Fused prep: k_node + k_pack_b + k_prep_wtf + k_prep_wl1 in ONE dispatch
// (branch by blockIdx range; all verified-individually r5-r18 logic unchanged)
__global__ void k_prep_all(
    const float* __restrict__ x, const float* __restrict__ Wn,
    const float* __restrict__ bn, float* __restrict__ h, int N, int nbNode,
    const float* __restrict__ W2, u16* __restrict__ Bph, int nbPack,
    const float* __restrict__ Wih, const float* __restrict__ Whh,
    u16* __restrict__ WpI, u16* __restrict__ WpH, int nbWtf,
    const float* __restrict__ Wl1, u16* __restrict__ Wp1) {
  int b = blockIdx.x;
  if (b < nbNode) {
    int tid = b * 256 + threadIdx.x;
    if (tid >= N * 64) return;
    int n = tid >> 6, f = tid & 63;
    float acc = bn[f];
    for (int k = 0; k < 8; ++k) acc += x[(size_t)n * 8 + k] * Wn[k * 64 + f];
    h[tid] = fmaxf(acc, 0.0f);
  } else if (b < nbNode + nbPack) {
    int tid = (b - nbNode) * 256 + threadIdx.x;
    if (tid >= 128 * 4096) return;
    int j = tid & 7;
    int lane = (tid >> 3) & 63;
    int nt = (tid >> 9) & 3;
    int ks = (tid >> 11) & 3;
    int d = tid >> 13;
    int c = lane & 15, q = lane >> 4;
    int k = ks * 32 + q * 8 + j;
    int n = d * 64 + nt * 16 + c;
    Bph[tid] = f2bf(W2[(size_t)k * 4096 + n]);
  } else if (b < nbNode + nbPack + nbWtf) {
    int tid = (b - nbNode - nbPack) * 256 + threadIdx.x;
    if (tid >= 2 * 12288) return;
    int w = tid / 12288;
    int r = tid - w * 12288;
    int jj = r & 7;
    int lane = (r >> 3) & 63;
    int t = r >> 9;
    int nt = t % 12, ks = t / 12;
    int c = lane & 15, q = lane >> 4;
    int j = nt * 16 + c;
    int k = ks * 32 + q * 8 + jj;
    const float* W = w ? Whh : Wih;
    u16* Wp = w ? WpH : WpI;
    Wp[r] = f2bf(W[j * 64 + k]);
  } else {
    int tid = (b - nbNode - nbPack - nbWtf) * 256 + threadIdx.x;
    if (tid >= 3 * 8 * 64 * 8) return;
    int j = tid & 7;
    int lane = (tid >> 3) & 63;
    int nt = (tid >> 9) & 7;
    int ks = tid >> 12;
    int c = lane & 15, q = lane >> 4;
    int k = ks * 32 + q * 8 + j;
    int n = nt * 16 + c;
    Wp1[tid] = f2bf((k < 72) ? Wl1[k * 128 + n] : 0.0f);
  }
}

// Fused conv, r23: occupancy 3 blocks/CU + d-split.
//  - grid (E/128, 2): each block does 32 d (half range), 782 blocks total
//  - LDS cut to 49664 B: 2 B-panels (32K) + hsT[32][132] (16.9K); b2 now
//    prefetched from global (L2-hot) into regs one iter ahead
//  - 12 waves/CU (3/SIMD) for pipe phase-decorrelation (was 8)
//  - msgp rows 128-wide: [half0 f0..63 | half1 f0..63]; GRU sums halves
__global__ __launch_bounds__(256, 3) void k_conv_fused(
    const u16* __restrict__ Ahi, const u16* __restrict__ Bph,
    const float* __restrict__ b2, const float* __restrict__ h,
    const int* __restrict__ src, const int* __restrict__ pos,
    float* __restrict__ msgp, int E) {
  __shared__ __align__(16) u16 sB[2][8192];     // 2 x 16 KB B panels
  __shared__ __align__(16) float hsT[32 * 132]; // h[src[e], d0+dl] transposed
  int m0 = blockIdx.x * 128;
  int d0 = blockIdx.y * 32;
  int tid = threadIdx.x;
  int wave = tid >> 6, lane = tid & 63;
  int mw = wave >> 1, fw = wave & 1;
  int c = lane & 15, q = lane >> 4;

  auto stageB = [&](int d, int b) {
    const u16* gp = Bph + (size_t)d * 8192 + wave * 2048 + lane * 8;
    u16* lp = &sB[b][wave * 2048];
#pragma unroll
    for (int i = 0; i < 4; ++i)
      __builtin_amdgcn_global_load_lds(
          (const __attribute__((address_space(1))) unsigned int*)(gp + i * 512),
          (__attribute__((address_space(3))) unsigned int*)(lp + i * 512), 16, 0, 0);
  };

  stageB(d0, 0);  // first panel in flight under the prologue

  // A fragments: 4 m-tiles x 4 k-slices, global->reg, held for whole kernel
  short8v afr[4][4];
#pragma unroll
  for (int mt = 0; mt < 4; ++mt) {
    int gr = m0 + mw * 64 + mt * 16 + c;
    if (gr >= E) gr = E - 1;
    const u16* ap = Ahi + (size_t)gr * 128 + q * 8;
#pragma unroll
    for (int ks = 0; ks < 4; ++ks) afr[mt][ks] = *(const short8v*)(ap + ks * 32);
  }

  // hsT: transposed stage of h[src[e], d0:d0+32]
#pragma unroll
  for (int p = 0; p < 4; ++p) {
    int slot = p * 256 + tid;
    int r = slot >> 3, s = slot & 7;  // edge r, d-quad s
    int ge = m0 + r;
    if (ge >= E) ge = E - 1;
    int sn = src[ge];
    float4 v = *(const float4*)(h + (size_t)sn * 64 + d0 + s * 4);
    hsT[(s * 4 + 0) * 132 + r] = v.x;
    hsT[(s * 4 + 1) * 132 + r] = v.y;
    hsT[(s * 4 + 2) * 132 + r] = v.z;
    hsT[(s * 4 + 3) * 132 + r] = v.w;
  }
  // b2 for dl=0 into regs (L2-hot)
  float b2v0 = b2[(size_t)d0 * 64 + fw * 32 + c];
  float b2v1 = b2[(size_t)d0 * 64 + fw * 32 + 16 + c];
  __syncthreads();  // panel0 + hsT ready

  float msg[4][2][4];
#pragma unroll
  for (int mt = 0; mt < 4; ++mt)
#pragma unroll
    for (int nt = 0; nt < 2; ++nt)
#pragma unroll
      for (int r = 0; r < 4; ++r) msg[mt][nt][r] = 0.0f;

  int cur = 0;
  for (int dl = 0; dl < 32; ++dl) {
    float nb0 = 0.f, nb1 = 0.f;
    if (dl < 31) {
      stageB(d0 + dl + 1, cur ^ 1);  // in flight during compute
      nb0 = b2[(size_t)(d0 + dl + 1) * 64 + fw * 32 + c];
      nb1 = b2[(size_t)(d0 + dl + 1) * 64 + fw * 32 + 16 + c];
    }
    float4v acc[4][2];
#pragma unroll
    for (int mt = 0; mt < 4; ++mt)
#pragma unroll
      for (int nt = 0; nt < 2; ++nt) acc[mt][nt] = (float4v){0.f, 0.f, 0.f, 0.f};
    __builtin_amdgcn_s_setprio(1);
#pragma unroll
    for (int ks = 0; ks < 4; ++ks) {
      short8v b0 = *(const short8v*)(&sB[cur][ks * 2048 + fw * 1024 + lane * 8]);
      short8v b1 = *(const short8v*)(&sB[cur][ks * 2048 + fw * 1024 + 512 + lane * 8]);
#pragma unroll
      for (int mt = 0; mt < 4; ++mt) {
        acc[mt][0] = __builtin_amdgcn_mfma_f32_16x16x32_bf16(afr[mt][ks], b0, acc[mt][0], 0, 0, 0);
        acc[mt][1] = __builtin_amdgcn_mfma_f32_16x16x32_bf16(afr[mt][ks], b1, acc[mt][1], 0, 0, 0);
      }
    }
    __builtin_amdgcn_s_setprio(0);
#pragma unroll
    for (int mt = 0; mt < 4; ++mt) {
      float4 hd4 = *(const float4*)(&hsT[dl * 132 + mw * 64 + mt * 16 + q * 4]);
      float hd[4] = {hd4.x, hd4.y, hd4.z, hd4.w};
#pragma unroll
      for (int r = 0; r < 4; ++r) {
        msg[mt][0][r] += hd[r] * (acc[mt][0][r] + b2v0);
        msg[mt][1][r] += hd[r] * (acc[mt][1][r] + b2v1);
      }
    }
    __syncthreads();  // all reads of sB[cur] done; stage(dl+1) complete
    b2v0 = nb0; b2v1 = nb1;
    cur ^= 1;
  }

  // stores pre-permuted to CSR slot order; d-half offset in 128-wide row
#pragma unroll
  for (int mt = 0; mt < 4; ++mt) {
#pragma unroll
    for (int r = 0; r < 4; ++r) {
      int e = m0 + mw * 64 + mt * 16 + q * 4 + r;
      if (e < E) {
        int pe = pos[e];
        float* mp = msgp + (size_t)pe * 128 + blockIdx.y * 64 + fw * 32 + c;
#pragma unroll
        for (int nt = 0; nt < 2; ++nt) mp[nt * 16] = msg[mt][nt][r];
      }
    }
  }
}

// MFMA GRU, r23: gathers 128-wide msgp rows (sums the two d-half contributions).
__global__ __launch_bounds__(256, 2) void k_gru_mfma(
    const float* __restrict__ msgp, const int* __restrict__ row,
    const float* __restrict__ cb, const u16* __restrict__ WpI,
    const u16* __restrict__ WpH, const float* __restrict__ bih,
    const float* __restrict__ bhh, const float* __restrict__ hin,
    float* __restrict__ hout, int N) {
  __shared__ __align__(16) u16 sM[64 * 72];
  __shared__ __align__(16) u16 sH[64 * 72];
  __shared__ __align__(16) float sHf[64 * 68];
  __shared__ int sRow[65];
  int n0 = blockIdx.x * 64;
  int tid = threadIdx.x;
  if (tid < 65) {
    int idx = n0 + tid;
    sRow[tid] = row[(idx <= N) ? idx : N];
  }
  __syncthreads();
  {
    int nl = tid >> 4, fq = tid & 15;
    float4 cbv = *(const float4*)(cb + fq * 4);
#pragma unroll
    for (int pass = 0; pass < 4; ++pass) {
      int n = pass * 16 + nl;
      int gn = n0 + n;
      bool real = (gn < N);
      int b0 = sRow[n], b1 = sRow[n + 1];
      if (!real) b1 = b0;
      float4 av = {0.f, 0.f, 0.f, 0.f};
      for (int j = b0; j < b1; ++j) {
        float4 m0 = *(const float4*)(msgp + (size_t)j * 128 + fq * 4);
        float4 m1 = *(const float4*)(msgp + (size_t)j * 128 + 64 + fq * 4);
        av.x += m0.x + m1.x; av.y += m0.y + m1.y;
        av.z += m0.z + m1.z; av.w += m0.w + m1.w;
      }
      float cf = fmaxf((float)(b1 - b0), 1.0f);
      int hgn = real ? gn : N - 1;
      float4 hv = *(const float4*)(hin + (size_t)hgn * 64 + fq * 4);
      float m0v = fmaxf(av.x / cf + cbv.x, 0.0f);
      float m1v = fmaxf(av.y / cf + cbv.y, 0.0f);
      float m2v = fmaxf(av.z / cf + cbv.z, 0.0f);
      float m3v = fmaxf(av.w / cf + cbv.w, 0.0f);
      ushort4 mu; mu.x = f2bf(m0v); mu.y = f2bf(m1v); mu.z = f2bf(m2v); mu.w = f2bf(m3v);
      ushort4 hu; hu.x = f2bf(hv.x); hu.y = f2bf(hv.y); hu.z = f2bf(hv.z); hu.w = f2bf(hv.w);
      *(ushort4*)(&sM[n * 72 + fq * 4]) = mu;
      *(ushort4*)(&sH[n * 72 + fq * 4]) = hu;
      *(float4*)(&sHf[n * 68 + fq * 4]) = hv;
    }
  }
  __syncthreads();
  int wave = tid >> 6, lane = tid & 63;
  int c = lane & 15, q = lane >> 4;
  short8v am[2], ah[2];
#pragma unroll
  for (int ks = 0; ks < 2; ++ks) {
    am[ks] = *(const short8v*)(&sM[(wave * 16 + c) * 72 + ks * 32 + q * 8]);
    ah[ks] = *(const short8v*)(&sH[(wave * 16 + c) * 72 + ks * 32 + q * 8]);
  }
  float4v accRZ[8], accN[4], accHN[4];
#pragma unroll
  for (int i = 0; i < 8; ++i) accRZ[i] = (float4v){0.f, 0.f, 0.f, 0.f};
#pragma unroll
  for (int i = 0; i < 4; ++i) {
    accN[i] = (float4v){0.f, 0.f, 0.f, 0.f};
    accHN[i] = (float4v){0.f, 0.f, 0.f, 0.f};
  }
#pragma unroll
  for (int ks = 0; ks < 2; ++ks) {
#pragma unroll
    for (int nt = 0; nt < 8; ++nt) {
      short8v bI = *(const short8v*)(WpI + ((size_t)(ks * 12 + nt) * 64 + lane) * 8);
      short8v bH = *(const short8v*)(WpH + ((size_t)(ks * 12 + nt) * 64 + lane) * 8);
      accRZ[nt] = __builtin_amdgcn_mfma_f32_16x16x32_bf16(am[ks], bI, accRZ[nt], 0, 0, 0);
      accRZ[nt] = __builtin_amdgcn_mfma_f32_16x16x32_bf16(ah[ks], bH, accRZ[nt], 0, 0, 0);
    }
#pragma unroll
    for (int nt = 0; nt < 4; ++nt) {
      short8v bI = *(const short8v*)(WpI + ((size_t)(ks * 12 + 8 + nt) * 64 + lane) * 8);
      short8v bH = *(const short8v*)(WpH + ((size_t)(ks * 12 + 8 + nt) * 64 + lane) * 8);
      accN[nt] = __builtin_amdgcn_mfma_f32_16x16x32_bf16(am[ks], bI, accN[nt], 0, 0, 0);
      accHN[nt] = __builtin_amdgcn_mfma_f32_16x16x32_bf16(ah[ks], bH, accHN[nt], 0, 0, 0);
    }
  }
#pragma unroll
  for (int nt = 0; nt < 4; ++nt) {
    int f = nt * 16 + c;
    float brz_r = bih[f] + bhh[f];
    float brz_z = bih[64 + f] + bhh[64 + f];
    float bin = bih[128 + f];
    float bhn = bhh[128 + f];
#pragma unroll
    for (int r = 0; r < 4; ++r) {
      int nl = wave * 16 + q * 4 + r;
      int gn = n0 + nl;
      float rr = sigm(accRZ[nt][r] + brz_r);
      float zz = sigm(accRZ[nt + 4][r] + brz_z);
      float ng = tanhf(accN[nt][r] + bin + rr * (accHN[nt][r] + bhn));
      float hv = sHf[nl * 68 + f];
      if (gn < N) hout[(size_t)gn * 64 + f] = (1.0f - zz) * ng + zz * hv;
    }
  }
}

// MFMA final MLP, r23: staging vectorized (float4 h-gather; was 48 scalar
// loads/thread). 4 threads/edge: each covers 16 f via 4+4 float4 loads.
__global__ __launch_bounds__(256) void k_final_mfma(
    const float* __restrict__ h, const float* __restrict__ ea3,
    const int* __restrict__ idx3, const u16* __restrict__ Wp1,
    const float* __restrict__ bl1, const float* __restrict__ Wl2,
    const float* __restrict__ bl2, float* __restrict__ out, int E3) {
  __shared__ __align__(16) u16 sF[64 * 104];
  int e0 = blockIdx.x * 64;
  int tid = threadIdx.x;
  {
    int er = tid >> 2;
    int part = tid & 3;
    int ge = e0 + er;
    int gc = (ge < E3) ? ge : E3 - 1;
    int a = idx3[gc], b = idx3[E3 + gc];
    const float* pa = h + (size_t)a * 64 + part * 16;
    const float* pb = h + (size_t)b * 64 + part * 16;
#pragma unroll
    for (int u = 0; u < 4; ++u) {
      float4 va = *(const float4*)(pa + u * 4);
      float4 vb = *(const float4*)(pb + u * 4);
      ushort4 mu;
      mu.x = f2bf(0.5f * (va.x + vb.x));
      mu.y = f2bf(0.5f * (va.y + vb.y));
      mu.z = f2bf(0.5f * (va.z + vb.z));
      mu.w = f2bf(0.5f * (va.w + vb.w));
      *(ushort4*)(&sF[er * 104 + part * 16 + u * 4]) = mu;
    }
    if (part == 0) {
      float4 e0v = *(const float4*)(ea3 + (size_t)gc * 8);
      float4 e1v = *(const float4*)(ea3 + (size_t)gc * 8 + 4);
      ushort4 u0, u1;
      u0.x = f2bf(e0v.x); u0.y = f2bf(e0v.y); u0.z = f2bf(e0v.z); u0.w = f2bf(e0v.w);
      u1.x = f2bf(e1v.x); u1.y = f2bf(e1v.y); u1.z = f2bf(e1v.z); u1.w = f2bf(e1v.w);
      *(ushort4*)(&sF[er * 104 + 64]) = u0;
      *(ushort4*)(&sF[er * 104 + 68]) = u1;
    } else {
      ushort4 z = {0, 0, 0, 0};
      *(ushort4*)(&sF[er * 104 + 72 + (part - 1) * 8]) = z;
      *(ushort4*)(&sF[er * 104 + 76 + (part - 1) * 8]) = z;
    }
  }
  __syncthreads();
  int wave = tid >> 6, lane = tid & 63;
  int c = lane & 15, q = lane >> 4;
  float4v acc[8];
#pragma unroll
  for (int nt = 0; nt < 8; ++nt) acc[nt] = (float4v){0.f, 0.f, 0.f, 0.f};
#pragma unroll
  for (int ks = 0; ks < 3; ++ks) {
    short8v af = *(const short8v*)(&sF[(wave * 16 + c) * 104 + ks * 32 + q * 8]);
#pragma unroll
    for (int nt = 0; nt < 8; ++nt) {
      short8v bf = *(const short8v*)(Wp1 + ((size_t)(ks * 8 + nt) * 64 + lane) * 8);
      acc[nt] = __builtin_amdgcn_mfma_f32_16x16x32_bf16(af, bf, acc[nt], 0, 0, 0);
    }
  }
  float v[4] = {0.f, 0.f, 0.f, 0.f};
#pragma unroll
  for (int nt = 0; nt < 8; ++nt) {
    int n = nt * 16 + c;
    float b1 = bl1[n];
    float w2 = Wl2[n];
#pragma unroll
    for (int r = 0; r < 4; ++r) v[r] += fmaxf(acc[nt][r] + b1, 0.0f) * w2;
  }
#pragma unroll
  for (int off = 1; off < 16; off <<= 1) {
#pragma unroll
    for (int r = 0; r < 4; ++r) v[r] += __shfl_xor(v[r], off);
  }
  if (c == 0) {
    float b2v = bl2[0];
#pragma unroll
    for (int r = 0; r < 4; ++r) {
      int e = e0 + wave * 16 + q * 4 + r;
      if (e < E3) out[e] = v[r] + b2v;
    }
  }
}

extern "C" void kernel_launch(void* const* d_in, const int* in_sizes, int n_in,
                              void* d_out, int out_size, void* d_ws, size_t ws_size,
                              hipStream_t stream) {
  const float* x          = (const float*)d_in[0];
  const float* edge_attr  = (const float*)d_in[1];
  const float* edge_attr3 = (const float*)d_in[2];
  const int*   edge_index = (const int*)d_in[3];
  const int*   edge_index3= (const int*)d_in[4];
  const float* W_node = (const float*)d_in[5];
  const float* b_node = (const float*)d_in[6];
  const float* W_ea   = (const float*)d_in[7];
  const float* b_ea   = (const float*)d_in[8];
  const float* W_e1   = (const float*)d_in[9];
  const float* b_e1   = (const float*)d_in[10];
  const float* W_e2   = (const float*)d_in[11];
  const float* b_e2   = (const float*)d_in[12];
  const float* conv_bias = (const float*)d_in[13];
  const float* W_ih   = (const float*)d_in[14];
  const float* b_ih   = (const float*)d_in[15];
  const float* W_hh   = (const float*)d_in[16];
  const float* b_hh   = (const float*)d_in[17];
  const float* W_l1   = (const float*)d_in[18];
  const float* b_l1   = (const float*)d_in[19];
  const float* W_l2   = (const float*)d_in[20];
  const float* b_l2   = (const float*)d_in[21];

  int N  = in_sizes[0] / 8;
  int E  = in_sizes[1] / 19;
  int E3 = in_sizes[2] / 8;

  char* p = (char*)d_ws;
  auto carve = [&](size_t bytes) -> void* {
    char* q = p;
    p += (bytes + 255) & ~(size_t)255;
    return (void*)q;
  };
  float* hA    = (float*)carve((size_t)N * 64 * 4);
  float* hB    = (float*)carve((size_t)N * 64 * 4);
  float* msgp  = (float*)carve((size_t)E * 128 * 4);
  int*   cnt   = (int*)carve((size_t)N * 4);
  int*   row   = (int*)carve((size_t)(N + 1) * 4);
  int*   cursor= (int*)carve((size_t)N * 4);
  int*   pos   = (int*)carve((size_t)E * 4);
  int*   bsum  = (int*)carve(256 * 4);
  u16*   Ahi   = (u16*)carve((size_t)E * 128 * 2);
  u16*   Bph   = (u16*)carve((size_t)128 * 4096 * 2);
  u16*   WpI   = (u16*)carve(12288 * 2);
  u16*   WpH   = (u16*)carve(12288 * 2);
  u16*   Wp1   = (u16*)carve(12288 * 2);

  const int* src = edge_index;
  const int* dst = edge_index + E;

  int nb = (N + 255) / 256;
  // CSR build (once)
  hipMemsetAsync(cnt, 0, (size_t)N * 4, stream);
  k_cnt<<<(E + 255) / 256, 256, 0, stream>>>(dst, cnt, E);
  k_scan1<<<nb, 256, 0, stream>>>(cnt, bsum, N);
  k_scan2<<<1, 256, 0, stream>>>(bsum, row, nb, N);
  k_scan3<<<nb, 256, 0, stream>>>(cnt, bsum, row, cursor, N);
  k_pos<<<(E + 255) / 256, 256, 0, stream>>>(dst, cursor, pos, E);

  k_edge_mlp<<<(E + 1) / 2, 256, 0, stream>>>(edge_attr, W_ea, b_ea, W_e1, b_e1, Ahi, E);
  int nbNode = ((size_t)N * 64 + 255) / 256;
  int nbPack = (128 * 4096 + 255) / 256;
  int nbWtf  = (2 * 12288 + 255) / 256;
  int nbWl1  = (12288 + 255) / 256;
  k_prep_all<<<nbNode + nbPack + nbWtf + nbWl1, 256, 0, stream>>>(
      x, W_node, b_node, hA, N, nbNode, W_e2, Bph, nbPack,
      W_ih, W_hh, WpI, WpH, nbWtf, W_l1, Wp1);

  float* hcur = hA;
  float* hnxt = hB;
  dim3 gconv((E + 127) / 128, 2);
  int ngru = (N + 63) / 64;
  for (int it = 0; it < 3; ++it) {
    k_conv_fused<<<gconv, 256, 0, stream>>>(Ahi, Bph, b_e2, hcur, src, pos, msgp, E);
    k_gru_mfma<<<ngru, 256, 0, stream>>>(msgp, row, conv_bias, WpI, WpH,
                                         b_ih, b_hh, hcur, hnxt, N);
    float* tmp = hcur; hcur = hnxt; hnxt = tmp;
  }
  k_final_mfma<<<(E3 + 63) / 64, 256, 0, stream>>>(hcur, edge_attr3, edge_index3, Wp1,
                                                   b_l1, W_l2, b_l2, (float*)d_out, E3);
}

// Round 6
// 398.002 us; speedup vs baseline: 1.1171x; 1.1171x over previous
//
#include <hip/hip_runtime.h>

typedef unsigned short u16;
typedef unsigned int u32;
typedef __attribute__((ext_vector_type(8))) short short8v;
typedef __attribute__((ext_vector_type(4))) float float4v;

__device__ __forceinline__ float sigm(float x) { return 1.0f / (1.0f + __expf(-x)); }
__device__ __forceinline__ u16 f2bf(float f) {
  u32 u = __float_as_uint(f);
  u32 r = (u + 0x7fffu + ((u >> 16) & 1u)) >> 16;
  return (u16)r;
}
__device__ __forceinline__ float bf2f(u16 w) { return __uint_as_float(((u32)w) << 16); }

__global__ void k_cnt(const int* __restrict__ dst, int* __restrict__ cnt, int E) {
  int e = blockIdx.x * blockDim.x + threadIdx.x;
  if (e < E) atomicAdd(&cnt[dst[e]], 1);
}

// --- parallel scan: scan1 block sums -> scan2 scan of ~98 sums -> scan3 local scan ---
__global__ void k_scan1(const int* __restrict__ cnt, int* __restrict__ bsum, int N) {
  __shared__ int ws[4];
  int t = threadIdx.x;
  int i = blockIdx.x * 256 + t;
  int v = (i < N) ? cnt[i] : 0;
  int s = v;
  for (int off = 1; off < 64; off <<= 1) s += __shfl_xor(s, off);
  int wid = t >> 6, lane = t & 63;
  if (lane == 0) ws[wid] = s;
  __syncthreads();
  if (t == 0) bsum[blockIdx.x] = ws[0] + ws[1] + ws[2] + ws[3];
}

__global__ void k_scan2(int* __restrict__ bsum, int* __restrict__ row, int nb, int N) {
  __shared__ int s[256];
  int t = threadIdx.x;
  if (t < nb) s[t] = bsum[t];
  __syncthreads();
  if (t == 0) {
    int run = 0;
    for (int i = 0; i < nb; ++i) { int x = s[i]; s[i] = run; run += x; }
    row[N] = run;
  }
  __syncthreads();
  if (t < nb) bsum[t] = s[t];
}

__global__ void k_scan3(const int* __restrict__ cnt, const int* __restrict__ bsum,
                        int* __restrict__ row, int* __restrict__ cursor, int N) {
  __shared__ int ws[4];
  int t = threadIdx.x;
  int i = blockIdx.x * 256 + t;
  int v = (i < N) ? cnt[i] : 0;
  int lane = t & 63, wid = t >> 6;
  int incl = v;
  for (int off = 1; off < 64; off <<= 1) {
    int u = __shfl_up(incl, off);
    if (lane >= off) incl += u;
  }
  if (lane == 63) ws[wid] = incl;
  __syncthreads();
  int woff = bsum[blockIdx.x];
  for (int w = 0; w < wid; ++w) woff += ws[w];
  int excl = woff + incl - v;
  if (i < N) { row[i] = excl; cursor[i] = excl; }
}

// pos[e] = CSR slot of edge e (counting sort position among same-dst edges)
__global__ void k_pos(const int* __restrict__ dst, int* __restrict__ cursor,
                      int* __restrict__ pos, int E) {
  int e = blockIdx.x * blockDim.x + threadIdx.x;
  if (e < E) pos[e] = atomicAdd(&cursor[dst[e]], 1);
}

// hmid -> plain bf16; 2 edges/block, ea computed once in LDS   [verified r18]
__global__ __launch_bounds__(256) void k_edge_mlp(
    const float* __restrict__ ea_in, const float* __restrict__ Wea,
    const float* __restrict__ bea, const float* __restrict__ We1,
    const float* __restrict__ be1, u16* __restrict__ Ahi, int E) {
  __shared__ float att[2][19];
  __shared__ float ea[2][12];
  int half = threadIdx.x >> 7;
  int t = threadIdx.x & 127;
  int e = blockIdx.x * 2 + half;
  bool real = (e < E);
  int ee = real ? e : E - 1;
  if (t < 19) att[half][t] = ea_in[(size_t)ee * 19 + t];
  __syncthreads();
  if (t < 12) {
    float a = bea[t];
#pragma unroll
    for (int k = 0; k < 19; ++k) a += att[half][k] * Wea[k * 12 + t];
    ea[half][t] = fmaxf(a, 0.0f);
  }
  __syncthreads();
  float a = be1[t];
#pragma unroll
  for (int j = 0; j < 12; ++j) a += ea[half][j] * We1[j * 128 + t];
  if (real) Ahi[(size_t)e * 128 + t] = f2bf(fmaxf(a, 0.0f));
}

// Fused prep: k_node + k_pack_b + k_prep_wtf + k_prep_wl1 in ONE dispatch
__global__ void k_prep_all(
    const float* __restrict__ x, const float* __restrict__ Wn,
    const float* __restrict__ bn, float* __restrict__ h, int N, int nbNode,
    const float* __restrict__ W2, u16* __restrict__ Bph, int nbPack,
    const float* __restrict__ Wih, const float* __restrict__ Whh,
    u16* __restrict__ WpI, u16* __restrict__ WpH, int nbWtf,
    const float* __restrict__ Wl1, u16* __restrict__ Wp1) {
  int b = blockIdx.x;
  if (b < nbNode) {
    int tid = b * 256 + threadIdx.x;
    if (tid >= N * 64) return;
    int n = tid >> 6, f = tid & 63;
    float acc = bn[f];
    for (int k = 0; k < 8; ++k) acc += x[(size_t)n * 8 + k] * Wn[k * 64 + f];
    h[tid] = fmaxf(acc, 0.0f);
  } else if (b < nbNode + nbPack) {
    int tid = (b - nbNode) * 256 + threadIdx.x;
    if (tid >= 128 * 4096) return;
    int j = tid & 7;
    int lane = (tid >> 3) & 63;
    int nt = (tid >> 9) & 3;
    int ks = (tid >> 11) & 3;
    int d = tid >> 13;
    int c = lane & 15, q = lane >> 4;
    int k = ks * 32 + q * 8 + j;
    int n = d * 64 + nt * 16 + c;
    Bph[tid] = f2bf(W2[(size_t)k * 4096 + n]);
  } else if (b < nbNode + nbPack + nbWtf) {
    int tid = (b - nbNode - nbPack) * 256 + threadIdx.x;
    if (tid >= 2 * 12288) return;
    int w = tid / 12288;
    int r = tid - w * 12288;
    int jj = r & 7;
    int lane = (r >> 3) & 63;
    int t = r >> 9;
    int nt = t % 12, ks = t / 12;
    int c = lane & 15, q = lane >> 4;
    int j = nt * 16 + c;
    int k = ks * 32 + q * 8 + jj;
    const float* W = w ? Whh : Wih;
    u16* Wp = w ? WpH : WpI;
    Wp[r] = f2bf(W[j * 64 + k]);
  } else {
    int tid = (b - nbNode - nbPack - nbWtf) * 256 + threadIdx.x;
    if (tid >= 3 * 8 * 64 * 8) return;
    int j = tid & 7;
    int lane = (tid >> 3) & 63;
    int nt = (tid >> 9) & 7;
    int ks = tid >> 12;
    int c = lane & 15, q = lane >> 4;
    int k = ks * 32 + q * 8 + j;
    int n = nt * 16 + c;
    Wp1[tid] = f2bf((k < 72) ? Wl1[k * 128 + n] : 0.0f);
  }
}

// Fused conv, r24 = r21 structure (best measured: 73.6us) + bf16 msg stores.
//  - 64 d per block, 2-panel LDS dbuf via global_load_lds w16
//  - hsT[64][132] transposed h-stage: hd = one b128/mt; sb2h bf16
//  - msg stored bf16 64-wide pre-permuted (pos): WRITE 25 -> 6.25 MB
// LDS = 32768(Bdbuf) + 33792(hsT) + 8192(sb2h) = 74752 B -> 2 blk/CU.
__global__ __launch_bounds__(256, 2) void k_conv_fused(
    const u16* __restrict__ Ahi, const u16* __restrict__ Bph,
    const float* __restrict__ b2, const float* __restrict__ h,
    const int* __restrict__ src, const int* __restrict__ pos,
    u16* __restrict__ msgh, int E) {
  __shared__ __align__(16) u16 sB[2][8192];     // 2 x 16 KB B panels
  __shared__ __align__(16) float hsT[64 * 132]; // h[src[e], d] transposed: [d][edge]
  __shared__ __align__(16) u16 sb2h[4096];      // b2 as bf16
  int m0 = blockIdx.x * 128;
  int tid = threadIdx.x;
  int wave = tid >> 6, lane = tid & 63;
  int mw = wave >> 1, fw = wave & 1;
  int c = lane & 15, q = lane >> 4;

  auto stageB = [&](int d, int b) {
    const u16* gp = Bph + (size_t)d * 8192 + wave * 2048 + lane * 8;
    u16* lp = &sB[b][wave * 2048];
#pragma unroll
    for (int i = 0; i < 4; ++i)
      __builtin_amdgcn_global_load_lds(
          (const __attribute__((address_space(1))) unsigned int*)(gp + i * 512),
          (__attribute__((address_space(3))) unsigned int*)(lp + i * 512), 16, 0, 0);
  };

  stageB(0, 0);  // first panel in flight under the prologue

  // A fragments: 4 m-tiles x 4 k-slices, global->reg, held for whole kernel
  short8v afr[4][4];
#pragma unroll
  for (int mt = 0; mt < 4; ++mt) {
    int gr = m0 + mw * 64 + mt * 16 + c;
    if (gr >= E) gr = E - 1;
    const u16* ap = Ahi + (size_t)gr * 128 + q * 8;
#pragma unroll
    for (int ks = 0; ks < 4; ++ks) afr[mt][ks] = *(const short8v*)(ap + ks * 32);
  }

  // hsT: transposed stage of h[src[e], 0:64]
#pragma unroll
  for (int p = 0; p < 8; ++p) {
    int slot = p * 256 + tid;
    int r = slot >> 4, s = slot & 15;  // edge r, d-quad s
    int ge = m0 + r;
    if (ge >= E) ge = E - 1;
    int sn = src[ge];
    float4 v = *(const float4*)(h + (size_t)sn * 64 + s * 4);
    hsT[(s * 4 + 0) * 132 + r] = v.x;
    hsT[(s * 4 + 1) * 132 + r] = v.y;
    hsT[(s * 4 + 2) * 132 + r] = v.z;
    hsT[(s * 4 + 3) * 132 + r] = v.w;
  }
  // sb2h: all 4096 b2 values as bf16
  {
    int t16 = tid * 16;
#pragma unroll
    for (int u = 0; u < 4; ++u) {
      float4 v = *(const float4*)(b2 + t16 + u * 4);
      sb2h[t16 + u * 4 + 0] = f2bf(v.x);
      sb2h[t16 + u * 4 + 1] = f2bf(v.y);
      sb2h[t16 + u * 4 + 2] = f2bf(v.z);
      sb2h[t16 + u * 4 + 3] = f2bf(v.w);
    }
  }
  __syncthreads();  // panel0 + hsT + sb2h ready

  float msg[4][2][4];
#pragma unroll
  for (int mt = 0; mt < 4; ++mt)
#pragma unroll
    for (int nt = 0; nt < 2; ++nt)
#pragma unroll
      for (int r = 0; r < 4; ++r) msg[mt][nt][r] = 0.0f;

  int cur = 0;
  for (int dl = 0; dl < 64; ++dl) {
    if (dl < 63) stageB(dl + 1, cur ^ 1);
    float b2v0 = bf2f(sb2h[dl * 64 + fw * 32 + c]);
    float b2v1 = bf2f(sb2h[dl * 64 + fw * 32 + 16 + c]);
    float4v acc[4][2];
#pragma unroll
    for (int mt = 0; mt < 4; ++mt)
#pragma unroll
      for (int nt = 0; nt < 2; ++nt) acc[mt][nt] = (float4v){0.f, 0.f, 0.f, 0.f};
    __builtin_amdgcn_s_setprio(1);
#pragma unroll
    for (int ks = 0; ks < 4; ++ks) {
      short8v b0 = *(const short8v*)(&sB[cur][ks * 2048 + fw * 1024 + lane * 8]);
      short8v b1 = *(const short8v*)(&sB[cur][ks * 2048 + fw * 1024 + 512 + lane * 8]);
#pragma unroll
      for (int mt = 0; mt < 4; ++mt) {
        acc[mt][0] = __builtin_amdgcn_mfma_f32_16x16x32_bf16(afr[mt][ks], b0, acc[mt][0], 0, 0, 0);
        acc[mt][1] = __builtin_amdgcn_mfma_f32_16x16x32_bf16(afr[mt][ks], b1, acc[mt][1], 0, 0, 0);
      }
    }
    __builtin_amdgcn_s_setprio(0);
#pragma unroll
    for (int mt = 0; mt < 4; ++mt) {
      float4 hd4 = *(const float4*)(&hsT[dl * 132 + mw * 64 + mt * 16 + q * 4]);
      float hd[4] = {hd4.x, hd4.y, hd4.z, hd4.w};
#pragma unroll
      for (int r = 0; r < 4; ++r) {
        msg[mt][0][r] += hd[r] * (acc[mt][0][r] + b2v0);
        msg[mt][1][r] += hd[r] * (acc[mt][1][r] + b2v1);
      }
    }
    __syncthreads();
    cur ^= 1;
  }

  // bf16 stores pre-permuted to CSR slot order: GRU reads contiguous rows
#pragma unroll
  for (int mt = 0; mt < 4; ++mt) {
#pragma unroll
    for (int r = 0; r < 4; ++r) {
      int e = m0 + mw * 64 + mt * 16 + q * 4 + r;
      if (e < E) {
        int pe = pos[e];
        u16* mp = msgh + (size_t)pe * 64 + fw * 32 + c;
        mp[0] = f2bf(msg[mt][0][r]);
        mp[16] = f2bf(msg[mt][1][r]);
      }
    }
  }
}

// MFMA GRU, r24: bf16 msgh gather (6.4 MB stream, was 25.6 f32-128w).
__global__ __launch_bounds__(256, 2) void k_gru_mfma(
    const u16* __restrict__ msgh, const int* __restrict__ row,
    const float* __restrict__ cb, const u16* __restrict__ WpI,
    const u16* __restrict__ WpH, const float* __restrict__ bih,
    const float* __restrict__ bhh, const float* __restrict__ hin,
    float* __restrict__ hout, int N) {
  __shared__ __align__(16) u16 sM[64 * 72];
  __shared__ __align__(16) u16 sH[64 * 72];
  __shared__ __align__(16) float sHf[64 * 68];
  __shared__ int sRow[65];
  int n0 = blockIdx.x * 64;
  int tid = threadIdx.x;
  if (tid < 65) {
    int idx = n0 + tid;
    sRow[tid] = row[(idx <= N) ? idx : N];
  }
  __syncthreads();
  {
    int nl = tid >> 4, fq = tid & 15;
    float4 cbv = *(const float4*)(cb + fq * 4);
#pragma unroll
    for (int pass = 0; pass < 4; ++pass) {
      int n = pass * 16 + nl;
      int gn = n0 + n;
      bool real = (gn < N);
      int b0 = sRow[n], b1 = sRow[n + 1];
      if (!real) b1 = b0;
      float4 av = {0.f, 0.f, 0.f, 0.f};
      for (int j = b0; j < b1; ++j) {
        ushort4 mv = *(const ushort4*)(msgh + (size_t)j * 64 + fq * 4);
        av.x += bf2f(mv.x); av.y += bf2f(mv.y);
        av.z += bf2f(mv.z); av.w += bf2f(mv.w);
      }
      float cf = fmaxf((float)(b1 - b0), 1.0f);
      int hgn = real ? gn : N - 1;
      float4 hv = *(const float4*)(hin + (size_t)hgn * 64 + fq * 4);
      float m0v = fmaxf(av.x / cf + cbv.x, 0.0f);
      float m1v = fmaxf(av.y / cf + cbv.y, 0.0f);
      float m2v = fmaxf(av.z / cf + cbv.z, 0.0f);
      float m3v = fmaxf(av.w / cf + cbv.w, 0.0f);
      ushort4 mu; mu.x = f2bf(m0v); mu.y = f2bf(m1v); mu.z = f2bf(m2v); mu.w = f2bf(m3v);
      ushort4 hu; hu.x = f2bf(hv.x); hu.y = f2bf(hv.y); hu.z = f2bf(hv.z); hu.w = f2bf(hv.w);
      *(ushort4*)(&sM[n * 72 + fq * 4]) = mu;
      *(ushort4*)(&sH[n * 72 + fq * 4]) = hu;
      *(float4*)(&sHf[n * 68 + fq * 4]) = hv;
    }
  }
  __syncthreads();
  int wave = tid >> 6, lane = tid & 63;
  int c = lane & 15, q = lane >> 4;
  short8v am[2], ah[2];
#pragma unroll
  for (int ks = 0; ks < 2; ++ks) {
    am[ks] = *(const short8v*)(&sM[(wave * 16 + c) * 72 + ks * 32 + q * 8]);
    ah[ks] = *(const short8v*)(&sH[(wave * 16 + c) * 72 + ks * 32 + q * 8]);
  }
  float4v accRZ[8], accN[4], accHN[4];
#pragma unroll
  for (int i = 0; i < 8; ++i) accRZ[i] = (float4v){0.f, 0.f, 0.f, 0.f};
#pragma unroll
  for (int i = 0; i < 4; ++i) {
    accN[i] = (float4v){0.f, 0.f, 0.f, 0.f};
    accHN[i] = (float4v){0.f, 0.f, 0.f, 0.f};
  }
#pragma unroll
  for (int ks = 0; ks < 2; ++ks) {
#pragma unroll
    for (int nt = 0; nt < 8; ++nt) {
      short8v bI = *(const short8v*)(WpI + ((size_t)(ks * 12 + nt) * 64 + lane) * 8);
      short8v bH = *(const short8v*)(WpH + ((size_t)(ks * 12 + nt) * 64 + lane) * 8);
      accRZ[nt] = __builtin_amdgcn_mfma_f32_16x16x32_bf16(am[ks], bI, accRZ[nt], 0, 0, 0);
      accRZ[nt] = __builtin_amdgcn_mfma_f32_16x16x32_bf16(ah[ks], bH, accRZ[nt], 0, 0, 0);
    }
#pragma unroll
    for (int nt = 0; nt < 4; ++nt) {
      short8v bI = *(const short8v*)(WpI + ((size_t)(ks * 12 + 8 + nt) * 64 + lane) * 8);
      short8v bH = *(const short8v*)(WpH + ((size_t)(ks * 12 + 8 + nt) * 64 + lane) * 8);
      accN[nt] = __builtin_amdgcn_mfma_f32_16x16x32_bf16(am[ks], bI, accN[nt], 0, 0, 0);
      accHN[nt] = __builtin_amdgcn_mfma_f32_16x16x32_bf16(ah[ks], bH, accHN[nt], 0, 0, 0);
    }
  }
#pragma unroll
  for (int nt = 0; nt < 4; ++nt) {
    int f = nt * 16 + c;
    float brz_r = bih[f] + bhh[f];
    float brz_z = bih[64 + f] + bhh[64 + f];
    float bin = bih[128 + f];
    float bhn = bhh[128 + f];
#pragma unroll
    for (int r = 0; r < 4; ++r) {
      int nl = wave * 16 + q * 4 + r;
      int gn = n0 + nl;
      float rr = sigm(accRZ[nt][r] + brz_r);
      float zz = sigm(accRZ[nt + 4][r] + brz_z);
      float ng = tanhf(accN[nt][r] + bin + rr * (accHN[nt][r] + bhn));
      float hv = sHf[nl * 68 + f];
      if (gn < N) hout[(size_t)gn * 64 + f] = (1.0f - zz) * ng + zz * hv;
    }
  }
}

// MFMA final MLP, r23-vectorized staging   [verified r23]
__global__ __launch_bounds__(256) void k_final_mfma(
    const float* __restrict__ h, const float* __restrict__ ea3,
    const int* __restrict__ idx3, const u16* __restrict__ Wp1,
    const float* __restrict__ bl1, const float* __restrict__ Wl2,
    const float* __restrict__ bl2, float* __restrict__ out, int E3) {
  __shared__ __align__(16) u16 sF[64 * 104];
  int e0 = blockIdx.x * 64;
  int tid = threadIdx.x;
  {
    int er = tid >> 2;
    int part = tid & 3;
    int ge = e0 + er;
    int gc = (ge < E3) ? ge : E3 - 1;
    int a = idx3[gc], b = idx3[E3 + gc];
    const float* pa = h + (size_t)a * 64 + part * 16;
    const float* pb = h + (size_t)b * 64 + part * 16;
#pragma unroll
    for (int u = 0; u < 4; ++u) {
      float4 va = *(const float4*)(pa + u * 4);
      float4 vb = *(const float4*)(pb + u * 4);
      ushort4 mu;
      mu.x = f2bf(0.5f * (va.x + vb.x));
      mu.y = f2bf(0.5f * (va.y + vb.y));
      mu.z = f2bf(0.5f * (va.z + vb.z));
      mu.w = f2bf(0.5f * (va.w + vb.w));
      *(ushort4*)(&sF[er * 104 + part * 16 + u * 4]) = mu;
    }
    if (part == 0) {
      float4 e0v = *(const float4*)(ea3 + (size_t)gc * 8);
      float4 e1v = *(const float4*)(ea3 + (size_t)gc * 8 + 4);
      ushort4 u0, u1;
      u0.x = f2bf(e0v.x); u0.y = f2bf(e0v.y); u0.z = f2bf(e0v.z); u0.w = f2bf(e0v.w);
      u1.x = f2bf(e1v.x); u1.y = f2bf(e1v.y); u1.z = f2bf(e1v.z); u1.w = f2bf(e1v.w);
      *(ushort4*)(&sF[er * 104 + 64]) = u0;
      *(ushort4*)(&sF[er * 104 + 68]) = u1;
    } else {
      ushort4 z = {0, 0, 0, 0};
      *(ushort4*)(&sF[er * 104 + 72 + (part - 1) * 8]) = z;
      *(ushort4*)(&sF[er * 104 + 76 + (part - 1) * 8]) = z;
    }
  }
  __syncthreads();
  int wave = tid >> 6, lane = tid & 63;
  int c = lane & 15, q = lane >> 4;
  float4v acc[8];
#pragma unroll
  for (int nt = 0; nt < 8; ++nt) acc[nt] = (float4v){0.f, 0.f, 0.f, 0.f};
#pragma unroll
  for (int ks = 0; ks < 3; ++ks) {
    short8v af = *(const short8v*)(&sF[(wave * 16 + c) * 104 + ks * 32 + q * 8]);
#pragma unroll
    for (int nt = 0; nt < 8; ++nt) {
      short8v bf = *(const short8v*)(Wp1 + ((size_t)(ks * 8 + nt) * 64 + lane) * 8);
      acc[nt] = __builtin_amdgcn_mfma_f32_16x16x32_bf16(af, bf, acc[nt], 0, 0, 0);
    }
  }
  float v[4] = {0.f, 0.f, 0.f, 0.f};
#pragma unroll
  for (int nt = 0; nt < 8; ++nt) {
    int n = nt * 16 + c;
    float b1 = bl1[n];
    float w2 = Wl2[n];
#pragma unroll
    for (int r = 0; r < 4; ++r) v[r] += fmaxf(acc[nt][r] + b1, 0.0f) * w2;
  }
#pragma unroll
  for (int off = 1; off < 16; off <<= 1) {
#pragma unroll
    for (int r = 0; r < 4; ++r) v[r] += __shfl_xor(v[r], off);
  }
  if (c == 0) {
    float b2v = bl2[0];
#pragma unroll
    for (int r = 0; r < 4; ++r) {
      int e = e0 + wave * 16 + q * 4 + r;
      if (e < E3) out[e] = v[r] + b2v;
    }
  }
}

extern "C" void kernel_launch(void* const* d_in, const int* in_sizes, int n_in,
                              void* d_out, int out_size, void* d_ws, size_t ws_size,
                              hipStream_t stream) {
  const float* x          = (const float*)d_in[0];
  const float* edge_attr  = (const float*)d_in[1];
  const float* edge_attr3 = (const float*)d_in[2];
  const int*   edge_index = (const int*)d_in[3];
  const int*   edge_index3= (const int*)d_in[4];
  const float* W_node = (const float*)d_in[5];
  const float* b_node = (const float*)d_in[6];
  const float* W_ea   = (const float*)d_in[7];
  const float* b_ea   = (const float*)d_in[8];
  const float* W_e1   = (const float*)d_in[9];
  const float* b_e1   = (const float*)d_in[10];
  const float* W_e2   = (const float*)d_in[11];
  const float* b_e2   = (const float*)d_in[12];
  const float* conv_bias = (const float*)d_in[13];
  const float* W_ih   = (const float*)d_in[14];
  const float* b_ih   = (const float*)d_in[15];
  const float* W_hh   = (const float*)d_in[16];
  const float* b_hh   = (const float*)d_in[17];
  const float* W_l1   = (const float*)d_in[18];
  const float* b_l1   = (const float*)d_in[19];
  const float* W_l2   = (const float*)d_in[20];
  const float* b_l2   = (const float*)d_in[21];

  int N  = in_sizes[0] / 8;
  int E  = in_sizes[1] / 19;
  int E3 = in_sizes[2] / 8;

  char* p = (char*)d_ws;
  auto carve = [&](size_t bytes) -> void* {
    char* q = p;
    p += (bytes + 255) & ~(size_t)255;
    return (void*)q;
  };
  float* hA    = (float*)carve((size_t)N * 64 * 4);
  float* hB    = (float*)carve((size_t)N * 64 * 4);
  u16*   msgh  = (u16*)carve((size_t)E * 64 * 2);
  int*   cnt   = (int*)carve((size_t)N * 4);
  int*   row   = (int*)carve((size_t)(N + 1) * 4);
  int*   cursor= (int*)carve((size_t)N * 4);
  int*   pos   = (int*)carve((size_t)E * 4);
  int*   bsum  = (int*)carve(256 * 4);
  u16*   Ahi   = (u16*)carve((size_t)E * 128 * 2);
  u16*   Bph   = (u16*)carve((size_t)128 * 4096 * 2);
  u16*   WpI   = (u16*)carve(12288 * 2);
  u16*   WpH   = (u16*)carve(12288 * 2);
  u16*   Wp1   = (u16*)carve(12288 * 2);

  const int* src = edge_index;
  const int* dst = edge_index + E;

  int nb = (N + 255) / 256;
  // CSR build (once)
  hipMemsetAsync(cnt, 0, (size_t)N * 4, stream);
  k_cnt<<<(E + 255) / 256, 256, 0, stream>>>(dst, cnt, E);
  k_scan1<<<nb, 256, 0, stream>>>(cnt, bsum, N);
  k_scan2<<<1, 256, 0, stream>>>(bsum, row, nb, N);
  k_scan3<<<nb, 256, 0, stream>>>(cnt, bsum, row, cursor, N);
  k_pos<<<(E + 255) / 256, 256, 0, stream>>>(dst, cursor, pos, E);

  k_edge_mlp<<<(E + 1) / 2, 256, 0, stream>>>(edge_attr, W_ea, b_ea, W_e1, b_e1, Ahi, E);
  int nbNode = ((size_t)N * 64 + 255) / 256;
  int nbPack = (128 * 4096 + 255) / 256;
  int nbWtf  = (2 * 12288 + 255) / 256;
  int nbWl1  = (12288 + 255) / 256;
  k_prep_all<<<nbNode + nbPack + nbWtf + nbWl1, 256, 0, stream>>>(
      x, W_node, b_node, hA, N, nbNode, W_e2, Bph, nbPack,
      W_ih, W_hh, WpI, WpH, nbWtf, W_l1, Wp1);

  float* hcur = hA;
  float* hnxt = hB;
  int gconv = (E + 127) / 128;
  int ngru = (N + 63) / 64;
  for (int it = 0; it < 3; ++it) {
    k_conv_fused<<<gconv, 256, 0, stream>>>(Ahi, Bph, b_e2, hcur, src, pos, msgh, E);
    k_gru_mfma<<<ngru, 256, 0, stream>>>(msgh, row, conv_bias, WpI, WpH,
                                         b_ih, b_hh, hcur, hnxt, N);
    float* tmp = hcur; hcur = hnxt; hnxt = tmp;
  }
  k_final_mfma<<<(E3 + 63) / 64, 256, 0, stream>>>(hcur, edge_attr3, edge_index3, Wp1,
                                                   b_l1, W_l2, b_l2, (float*)d_out, E3);
}